// Round 7
// baseline (6395.036 us; speedup 1.0000x reference)
//
#include <hip/hip_runtime.h>
#include <cstdio>

#define N_NODES 100000
#define NPAD    100096      // 782*128 padded row count (gemm reads full tiles)
#define NTILES  782         // ceil(100000/128)
#define NE      320000
#define NCH     196         // ceil(100000/512)
#define WCO_OFF 3145728L    // 6*256*2048 inner W elems (quarter-Z layout)
#define OUT_ELEMS (N_NODES * 256)

typedef unsigned short ushort_t;
typedef unsigned short u16x4 __attribute__((ext_vector_type(4)));
typedef unsigned short u16x8 __attribute__((ext_vector_type(8)));
typedef _Float16       f16;
typedef _Float16       f16x8 __attribute__((ext_vector_type(8)));
typedef float          f32x4 __attribute__((ext_vector_type(4)));
typedef float          f32x4v __attribute__((ext_vector_type(4)));

__device__ __forceinline__ float bf2f(ushort_t u) {
    return __uint_as_float(((unsigned)u) << 16);
}
__device__ __forceinline__ ushort_t f2bf(float f) {
    unsigned u = __float_as_uint(f);
    u += 0x7FFFu + ((u >> 16) & 1u);   // round-to-nearest-even
    return (ushort_t)(u >> 16);
}
__device__ __forceinline__ ushort_t f2h(float f) {
    f16 h = (f16)f;
    return __builtin_bit_cast(ushort_t, h);
}
__device__ __forceinline__ float h2f(ushort_t u) {
    return (float)__builtin_bit_cast(f16, u);
}

// ---------------------------------------------------------------------------
// XCD-aware bijective block remap (m204 variant; handles nwg % 8 != 0).
// ---------------------------------------------------------------------------
__device__ __forceinline__ int xcd_remap(int pbid, int nwg) {
    int q = nwg >> 3, r = nwg & 7;
    int xcd = pbid & 7, idx = pbid >> 3;
    int base = (xcd < r) ? xcd * (q + 1) : r * (q + 1) + (xcd - r) * q;
    return base + idx;
}

// fast tanh: clamp + exp identity (abs err ~1e-6, invisible in fp16)
__device__ __forceinline__ float fast_tanh(float x) {
    x = fminf(fmaxf(x, -10.f), 10.f);
    float e = __expf(2.f * x);
    return (e - 1.f) / (e + 1.f);
}

__device__ __forceinline__ float gelu_f(float x) {
    return 0.5f * x * (1.f + erff(x * 0.70710678118654752f));
}

// ---------------------------------------------------------------------------
// dtype sniff on embed_table words. flag = 1 means float32 inputs.
// ---------------------------------------------------------------------------
__global__ __launch_bounds__(256) void detect_k(const unsigned* __restrict__ w0, int* __restrict__ flag) {
    __shared__ int lds[256];
    int t = threadIdx.x;
    int cnt = 0;
    for (int i = t; i < 2048; i += 256) {
        unsigned e = (w0[i] >> 7) & 0xFFu;
        cnt += (e >= 96u && e <= 140u) ? 1 : 0;
    }
    lds[t] = cnt; __syncthreads();
    for (int s = 128; s > 0; s >>= 1) {
        if (t < s) lds[t] += lds[t + s];
        __syncthreads();
    }
    if (t == 0) *flag = (lds[0] < 1024) ? 1 : 0;
}

// input element -> canonical fp16 bits
__device__ __forceinline__ ushort_t load_in(const void* p, long i, bool isf32) {
    return isf32 ? f2h(((const float*)p)[i]) : f2h(bf2f(((const ushort_t*)p)[i]));
}

// ---------------------------------------------------------------------------
// small-tensor fp16 canonicalization (ln scales/biases, dense W/b)
// ---------------------------------------------------------------------------
struct CvtArgs {
    const void* src[8];
    ushort_t*   dst[8];
    int         n[8];
};

__global__ __launch_bounds__(256) void cvt_k(CvtArgs a, const int* __restrict__ flag) {
    int ti = blockIdx.y;
    int n = a.n[ti];
    const void* s = a.src[ti];
    ushort_t* d = a.dst[ti];
    bool isf32 = (*flag != 0);
    for (int i = blockIdx.x * 256 + threadIdx.x; i < n; i += gridDim.x * 256)
        d[i] = load_in(s, i, isf32);
}

// ---------------------------------------------------------------------------
// LN-folded dense weight prep (runs after cvt_k):
//   inner rows wid in [0,1536): lay=wid>>8, c=wid&255, K=256
//     dWiS[wid*256+k] = dWi[c,k]*lsi[lay,k]; uwi[wid]=sum_k dWi*lsi;
//     w0i[wid] = sum_k dWi*lbi + dbi[lay,c]
//   out rows wid in [1536,2048): w2=wid-1536, b=w2>>8, c=w2&255, K=512
// Wave per row.
// ---------------------------------------------------------------------------
__global__ __launch_bounds__(256) void scale_w_k(const ushort_t* __restrict__ dWiC,
                                                 const ushort_t* __restrict__ lsiC,
                                                 const ushort_t* __restrict__ lbiC,
                                                 const ushort_t* __restrict__ dbiC,
                                                 const ushort_t* __restrict__ dWoC,
                                                 const ushort_t* __restrict__ lsoC,
                                                 const ushort_t* __restrict__ lboC,
                                                 const ushort_t* __restrict__ dboC,
                                                 ushort_t* __restrict__ dWiS,
                                                 float* __restrict__ uwi, float* __restrict__ w0i,
                                                 ushort_t* __restrict__ dWoS,
                                                 float* __restrict__ uwo, float* __restrict__ w0o) {
    int wid = blockIdx.x * 4 + (threadIdx.x >> 6);
    int l = threadIdx.x & 63;
    float u = 0.f, w0 = 0.f;
    if (wid < 1536) {
        int lay = wid >> 8, c = wid & 255;
        u16x4 wv = *(const u16x4*)(dWiC + (size_t)wid * 256 + l * 4);
        u16x4 sv = *(const u16x4*)(lsiC + lay * 256 + l * 4);
        u16x4 bv = *(const u16x4*)(lbiC + lay * 256 + l * 4);
        u16x4 ov;
        #pragma unroll
        for (int i = 0; i < 4; i++) {
            float W = h2f(wv[i]);
            float ws = W * h2f(sv[i]);
            ov[i] = f2h(ws);
            u += ws; w0 += W * h2f(bv[i]);
        }
        *(u16x4*)(dWiS + (size_t)wid * 256 + l * 4) = ov;
        #pragma unroll
        for (int m = 1; m < 64; m <<= 1) {
            u += __shfl_xor(u, m, 64); w0 += __shfl_xor(w0, m, 64);
        }
        if (l == 0) { uwi[wid] = u; w0i[wid] = w0 + h2f(dbiC[lay * 256 + c]); }
    } else if (wid < 2048) {
        int w2 = wid - 1536;
        int b = w2 >> 8, c = w2 & 255;
        u16x8 wv = *(const u16x8*)(dWoC + (size_t)w2 * 512 + l * 8);
        u16x8 sv = *(const u16x8*)(lsoC + b * 512 + l * 8);
        u16x8 bv = *(const u16x8*)(lboC + b * 512 + l * 8);
        u16x8 ov;
        #pragma unroll
        for (int i = 0; i < 8; i++) {
            float W = h2f(wv[i]);
            float ws = W * h2f(sv[i]);
            ov[i] = f2h(ws);
            u += ws; w0 += W * h2f(bv[i]);
        }
        *(u16x8*)(dWoS + (size_t)w2 * 512 + l * 8) = ov;
        #pragma unroll
        for (int m = 1; m < 64; m <<= 1) {
            u += __shfl_xor(u, m, 64); w0 += __shfl_xor(w0, m, 64);
        }
        if (l == 0) { uwo[w2] = u; w0o[w2] = w0 + h2f(dboC[b * 256 + c]); }
    }
}

// ---------------------------------------------------------------------------
// Weight pre-pack (dual dtype -> fp16), both stacks in quarter-Z layout.
// ---------------------------------------------------------------------------
__global__ __launch_bounds__(256) void pack_w(const void* __restrict__ eWi,
                                              const void* __restrict__ eWo,
                                              ushort_t* __restrict__ WC,
                                              const int* __restrict__ flag) {
    long idx = (long)blockIdx.x * 256 + threadIdx.x;
    bool isf32 = (*flag != 0);
    const long ELI = 6L * 4 * 256 * 512;     // 3,145,728
    const long ELO = 2L * 4 * 512 * 1024;    // 4,194,304
    if (idx < ELI) {
        int j = idx & 511;
        int o = (idx >> 9) & 255;
        int t = (idx >> 17) & 3;
        long l = idx >> 19;
        int q = o >> 6, oo = o & 63;
        int k = j & 255;
        int n = ((j < 256) ? 0 : 256) + t * 64 + oo;
        WC[l * 524288 + (long)q * 131072 + (long)n * 256 + k] = load_in(eWi, idx, isf32);
    } else if (idx < ELI + ELO) {
        long i2 = idx - ELI;
        int j = i2 & 1023;
        int o = (i2 >> 10) & 511;
        int t = (i2 >> 19) & 3;
        long b = i2 >> 21;
        int c = o >> 6, oo = o & 63;
        int k = j & 511;
        int n = ((j < 512) ? 0 : 256) + t * 64 + oo;
        WC[WCO_OFF + b * 2097152L + (long)c * 262144 + (long)n * 512 + k] = load_in(eWo, i2, isf32);
    }
}

// ---------------------------------------------------------------------------
// Embedding gather (dual dtype): S[v] = fp16(table[ids[v]])
// ---------------------------------------------------------------------------
__global__ __launch_bounds__(256) void embed_k(const int* __restrict__ ids,
                                               const void* __restrict__ tab,
                                               ushort_t* __restrict__ S,
                                               const int* __restrict__ flag) {
    int row = blockIdx.x * 4 + (threadIdx.x >> 6);
    int l = threadIdx.x & 63;
    if (row >= N_NODES) return;
    int id = ids[row];
    u16x4 v;
    if (*flag) {
        f32x4v fv = *(const f32x4v*)((const float*)tab + (size_t)id * 256 + l * 4);
        #pragma unroll
        for (int i = 0; i < 4; i++) v[i] = f2h(fv[i]);
    } else {
        u16x4 bv = *(const u16x4*)((const ushort_t*)tab + (size_t)id * 256 + l * 4);
        #pragma unroll
        for (int i = 0; i < 4; i++) v[i] = f2h(bf2f(bv[i]));
    }
    *(u16x4*)(S + (size_t)row * 256 + l * 4) = v;
}

// ---------------------------------------------------------------------------
// Output emit: internal fp16 -> harness dtype (f32 or bf16)
// ---------------------------------------------------------------------------
__global__ __launch_bounds__(256) void emit_k(const ushort_t* __restrict__ Bst, void* __restrict__ out,
                                              const int* __restrict__ flag) {
    long i = (long)blockIdx.x * 256 + threadIdx.x;
    if (i >= OUT_ELEMS) return;
    float v = h2f(Bst[i]);
    if (*flag) ((float*)out)[i] = v;
    else       ((ushort_t*)out)[i] = f2bf(v);
}

// ---------------------------------------------------------------------------
// CSR by target node
// ---------------------------------------------------------------------------
__global__ __launch_bounds__(256) void count_k(const int* __restrict__ tgt, int* __restrict__ counts) {
    int e = blockIdx.x * 256 + threadIdx.x;
    if (e < NE) atomicAdd(&counts[tgt[e]], 1);
}

__global__ __launch_bounds__(256) void scan1_k(const int* __restrict__ counts,
                                               int* __restrict__ incl, int* __restrict__ chsums) {
    __shared__ int lds[256];
    int c = blockIdx.x, t = threadIdx.x;
    int i0 = c * 512 + 2 * t;
    int a = (i0 < N_NODES) ? counts[i0] : 0;
    int b = (i0 + 1 < N_NODES) ? counts[i0 + 1] : 0;
    int ps = a + b;
    lds[t] = ps; __syncthreads();
    int x = ps;
    for (int off = 1; off < 256; off <<= 1) {
        int y = (t >= off) ? lds[t - off] : 0;
        __syncthreads();
        x += y; lds[t] = x;
        __syncthreads();
    }
    int excl = x - ps;
    if (i0 < N_NODES) incl[i0] = excl + a;
    if (i0 + 1 < N_NODES) incl[i0 + 1] = excl + a + b;
    if (t == 255) chsums[c] = x;
}

__global__ __launch_bounds__(256) void scan2_k(const int* __restrict__ chsums, int* __restrict__ chunkoff) {
    __shared__ int lds[256];
    int t = threadIdx.x;
    int v = (t < NCH) ? chsums[t] : 0;
    lds[t] = v; __syncthreads();
    int x = v;
    for (int off = 1; off < 256; off <<= 1) {
        int y = (t >= off) ? lds[t - off] : 0;
        __syncthreads();
        x += y; lds[t] = x;
        __syncthreads();
    }
    if (t <= NCH) chunkoff[t] = x - v;   // exclusive
}

__global__ __launch_bounds__(256) void scan3_k(const int* __restrict__ counts, const int* __restrict__ incl,
                                               const int* __restrict__ chunkoff,
                                               int* __restrict__ offsets, int* __restrict__ cursor) {
    int c = blockIdx.x, t = threadIdx.x;
    int base = chunkoff[c];
    #pragma unroll
    for (int k = 0; k < 2; k++) {
        int i = c * 512 + 2 * t + k;
        if (i < N_NODES) {
            int off = base + incl[i] - counts[i];
            offsets[i] = off;
            cursor[i] = off;
        }
    }
    if (c == 0 && t == 0) offsets[N_NODES] = chunkoff[NCH];
}

__global__ __launch_bounds__(256) void fill_k(const int* __restrict__ et, const int* __restrict__ src,
                                              const int* __restrict__ tgt,
                                              int* __restrict__ cursor, int* __restrict__ sorted) {
    int e = blockIdx.x * 256 + threadIdx.x;
    if (e < NE) {
        int pos = atomicAdd(&cursor[tgt[e]], 1);
        sorted[pos] = ((et[e] - 1) << 28) | src[e];
    }
}

// ---------------------------------------------------------------------------
// GEMM: C[localM, ldc] = A[localM, K] @ B[., K]^T  (fp16 row-major)
// 128x128 tile, BK=64, 4 waves, mfma_f32_16x16x32_f16, global_load_lds(16B).
// XCD-remapped block order for A-panel L2 reuse.
// EPI 2: LN-folded dense: val = rs_r*(acc - mean_r*u[c]) + w0[c]; tanh; fp16.
//        (A must be G = gelu(msg); B must be ls-scaled weights.)
// EPI 3: Cb[r*ldc+c] = fp16(acc)   (Z emit, unguarded/padded)
// ---------------------------------------------------------------------------
template<int EPI>
__global__ __launch_bounds__(256) void gemm_bt(const ushort_t* __restrict__ A,
                                               const ushort_t* __restrict__ B,
                                               int K, int ldc,
                                               ushort_t* __restrict__ Cb,
                                               const float2* __restrict__ MR,
                                               const float* __restrict__ uu,
                                               const float* __restrict__ w0t,
                                               int storeM) {
    __shared__ __align__(16) ushort_t As[128 * 64];
    __shared__ __align__(16) ushort_t Bs[128 * 64];
    const int tid = threadIdx.x;
    const int w = tid >> 6, l = tid & 63;
    const int wr = w >> 1, wc = w & 1;
    const int gx = gridDim.x;
    const int lbid = xcd_remap(blockIdx.y * gx + blockIdx.x, gx * gridDim.y);
    const long m0 = (long)(lbid / gx) * 128, n0 = (long)(lbid % gx) * 128;
    const int lr = l >> 3;
    const int lc = (l & 7) * 8;
    f32x4 acc[4][4];
    #pragma unroll
    for (int s = 0; s < 4; s++)
        #pragma unroll
        for (int n = 0; n < 4; n++) acc[s][n] = (f32x4){0.f, 0.f, 0.f, 0.f};

    for (int k0 = 0; k0 < K; k0 += 64) {
        #pragma unroll
        for (int q = 0; q < 4; q++) {
            int row = w * 32 + q * 8 + lr;
            const ushort_t* g = A + (m0 + row) * (long)K + k0 + lc;
            __builtin_amdgcn_global_load_lds(
                (__attribute__((address_space(1))) unsigned int*)(g),
                (__attribute__((address_space(3))) unsigned int*)(&As[row * 64 + lc]), 16, 0, 0);
        }
        #pragma unroll
        for (int q = 0; q < 4; q++) {
            int row = w * 32 + q * 8 + lr;
            const ushort_t* g = B + (n0 + row) * (long)K + k0 + lc;
            __builtin_amdgcn_global_load_lds(
                (__attribute__((address_space(1))) unsigned int*)(g),
                (__attribute__((address_space(3))) unsigned int*)(&Bs[row * 64 + lc]), 16, 0, 0);
        }
        __syncthreads();
        #pragma unroll
        for (int kk = 0; kk < 2; kk++) {
            f16x8 af[4], bfr[4];
            #pragma unroll
            for (int s = 0; s < 4; s++)
                af[s] = *(const f16x8*)&As[(wr * 64 + s * 16 + (l & 15)) * 64 + kk * 32 + (l >> 4) * 8];
            #pragma unroll
            for (int n = 0; n < 4; n++)
                bfr[n] = *(const f16x8*)&Bs[(wc * 64 + n * 16 + (l & 15)) * 64 + kk * 32 + (l >> 4) * 8];
            #pragma unroll
            for (int s = 0; s < 4; s++)
                #pragma unroll
                for (int n = 0; n < 4; n++)
                    acc[s][n] = __builtin_amdgcn_mfma_f32_16x16x32_f16(af[s], bfr[n], acc[s][n], 0, 0, 0);
        }
        __syncthreads();
    }
    const long rb = m0 + wr * 64 + ((l >> 4) << 2);
    const long cb = n0 + wc * 64 + (l & 15);
    #pragma unroll
    for (int s = 0; s < 4; s++) {
        #pragma unroll
        for (int n = 0; n < 4; n++) {
            long c = cb + n * 16;
            #pragma unroll
            for (int j = 0; j < 4; j++) {
                long r = rb + s * 16 + j;
                float val = acc[s][n][j];
                if constexpr (EPI == 2) {
                    if (r < storeM) {
                        float2 mr = MR[r];
                        float o = mr.y * (val - mr.x * uu[c]) + w0t[c];
                        Cb[r * ldc + c] = f2h(fast_tanh(o));
                    }
                } else {
                    Cb[r * ldc + c] = f2h(val);
                }
            }
        }
    }
}

// ---------------------------------------------------------------------------
// Split-A GEMM for out-layer Z: A = [A0 | A1] (two [.,256] fp16 buffers),
// K = 512 fixed, fp16 store (Z emit). XCD-remapped. Same tile structure.
// ---------------------------------------------------------------------------
__global__ __launch_bounds__(256) void gemm_bt2(const ushort_t* __restrict__ A0,
                                                const ushort_t* __restrict__ A1,
                                                const ushort_t* __restrict__ B,
                                                int ldc,
                                                ushort_t* __restrict__ Cb) {
    __shared__ __align__(16) ushort_t As[128 * 64];
    __shared__ __align__(16) ushort_t Bs[128 * 64];
    const int tid = threadIdx.x;
    const int w = tid >> 6, l = tid & 63;
    const int wr = w >> 1, wc = w & 1;
    const int gx = gridDim.x;
    const int lbid = xcd_remap(blockIdx.y * gx + blockIdx.x, gx * gridDim.y);
    const long m0 = (long)(lbid / gx) * 128, n0 = (long)(lbid % gx) * 128;
    const int lr = l >> 3;
    const int lc = (l & 7) * 8;
    f32x4 acc[4][4];
    #pragma unroll
    for (int s = 0; s < 4; s++)
        #pragma unroll
        for (int n = 0; n < 4; n++) acc[s][n] = (f32x4){0.f, 0.f, 0.f, 0.f};

    for (int k0 = 0; k0 < 512; k0 += 64) {
        const ushort_t* Ab = (k0 < 256) ? A0 : A1;
        const int kq = k0 & 255;
        #pragma unroll
        for (int q = 0; q < 4; q++) {
            int row = w * 32 + q * 8 + lr;
            const ushort_t* g = Ab + (m0 + row) * 256L + kq + lc;
            __builtin_amdgcn_global_load_lds(
                (__attribute__((address_space(1))) unsigned int*)(g),
                (__attribute__((address_space(3))) unsigned int*)(&As[row * 64 + lc]), 16, 0, 0);
        }
        #pragma unroll
        for (int q = 0; q < 4; q++) {
            int row = w * 32 + q * 8 + lr;
            const ushort_t* g = B + (n0 + row) * 512L + k0 + lc;
            __builtin_amdgcn_global_load_lds(
                (__attribute__((address_space(1))) unsigned int*)(g),
                (__attribute__((address_space(3))) unsigned int*)(&Bs[row * 64 + lc]), 16, 0, 0);
        }
        __syncthreads();
        #pragma unroll
        for (int kk = 0; kk < 2; kk++) {
            f16x8 af[4], bfr[4];
            #pragma unroll
            for (int s = 0; s < 4; s++)
                af[s] = *(const f16x8*)&As[(wr * 64 + s * 16 + (l & 15)) * 64 + kk * 32 + (l >> 4) * 8];
            #pragma unroll
            for (int n = 0; n < 4; n++)
                bfr[n] = *(const f16x8*)&Bs[(wc * 64 + n * 16 + (l & 15)) * 64 + kk * 32 + (l >> 4) * 8];
            #pragma unroll
            for (int s = 0; s < 4; s++)
                #pragma unroll
                for (int n = 0; n < 4; n++)
                    acc[s][n] = __builtin_amdgcn_mfma_f32_16x16x32_f16(af[s], bfr[n], acc[s][n], 0, 0, 0);
        }
        __syncthreads();
    }
    const long rb = m0 + wr * 64 + ((l >> 4) << 2);
    const long cb = n0 + wc * 64 + (l & 15);
    #pragma unroll
    for (int s = 0; s < 4; s++) {
        #pragma unroll
        for (int n = 0; n < 4; n++) {
            long c = cb + n * 16;
            #pragma unroll
            for (int j = 0; j < 4; j++) {
                long r = rb + s * 16 + j;
                Cb[r * ldc + c] = f2h(acc[s][n][j]);
            }
        }
    }
}

// ---------------------------------------------------------------------------
// Chunk-aggregate over Z + fused gelu + LN-stats accumulation.
// Z[u, n] fp16, n in [0,512): n = t*64+oo (agg/src), 256+t*64+oo (self*deg_t).
// g = gelu(msg) is FINAL for this col chunk -> write G[v, q*64+oo],
// wave-reduce sum(g), sum(g^2) -> atomic into Sg[v], Sq[v].
// ---------------------------------------------------------------------------
__global__ __launch_bounds__(256) void agg_q(const ushort_t* __restrict__ Z,
                                             const int* __restrict__ offsets,
                                             const int* __restrict__ sorted,
                                             ushort_t* __restrict__ G, int mld, int q,
                                             float* __restrict__ Sg, float* __restrict__ Sq) {
    int v = blockIdx.x * 4 + (threadIdx.x >> 6);
    int l = threadIdx.x & 63;
    if (v >= NPAD) return;
    ushort_t* mp = G + (size_t)v * mld + (q << 6) + l;
    if (v >= N_NODES) { *mp = 0; return; }
    float acc = 0.f;
    int d0 = 0, d1 = 0, d2 = 0, d3 = 0;
    int beg = offsets[v], end = offsets[v + 1];
    for (int e = beg; e < end; ++e) {
        int pk = sorted[e];
        int t = pk >> 28;                 // 0..3
        int s = pk & 0x0FFFFFFF;
        acc += h2f(Z[(size_t)s * 512 + (t << 6) + l]);
        d0 += (t == 0); d1 += (t == 1); d2 += (t == 2); d3 += (t == 3);
    }
    const ushort_t* zs = Z + (size_t)v * 512 + 256 + l;
    if (d0) acc += (float)d0 * h2f(zs[0]);
    if (d1) acc += (float)d1 * h2f(zs[64]);
    if (d2) acc += (float)d2 * h2f(zs[128]);
    if (d3) acc += (float)d3 * h2f(zs[192]);
    float g = gelu_f(acc);
    *mp = f2h(g);
    float sg = g, sq = g * g;
    #pragma unroll
    for (int m = 1; m < 64; m <<= 1) {
        sg += __shfl_xor(sg, m, 64);
        sq += __shfl_xor(sq, m, 64);
    }
    if (l == 0) {
        atomicAdd(&Sg[v], sg);
        atomicAdd(&Sq[v], sq);
    }
}

// ---------------------------------------------------------------------------
// Per-node LN stats: MR[v] = (mean, rsqrt(var+eps)); re-zero Sg/Sq for reuse.
// ---------------------------------------------------------------------------
__global__ __launch_bounds__(256) void stats_k(float* __restrict__ Sg, float* __restrict__ Sq,
                                               float2* __restrict__ MR, float inv) {
    int v = blockIdx.x * 256 + threadIdx.x;
    if (v >= N_NODES) return;
    float mean = Sg[v] * inv;
    float var = fmaxf(Sq[v] * inv - mean * mean, 0.f);
    MR[v] = make_float2(mean, rsqrtf(var + 1e-5f));
    Sg[v] = 0.f; Sq[v] = 0.f;
}

// ---------------------------------------------------------------------------
extern "C" void kernel_launch(void* const* d_in, const int* in_sizes, int n_in,
                              void* d_out, int out_size, void* d_ws, size_t ws_size,
                              hipStream_t stream) {
    const int* ids = (const int*)d_in[0];
    const int* te = (const int*)d_in[1];
    const int* et = te;
    const int* esrc = te + NE;
    const int* etgt = te + 2 * NE;
    const void* tab = d_in[2];
    const void* eWi = d_in[3];
    const void* lsi = d_in[4];
    const void* lbi = d_in[5];
    const void* dWi = d_in[6];
    const void* dbi = d_in[7];
    const void* eWo = d_in[8];
    const void* lso = d_in[9];
    const void* lbo = d_in[10];
    const void* dWo = d_in[11];
    const void* dbo = d_in[12];

    char* w = (char*)d_ws;
    auto alloc = [&](size_t bytes) -> char* {
        char* p = w; w += (bytes + 255) & ~(size_t)255; return p;
    };
    ushort_t* A    = (ushort_t*)alloc((size_t)NPAD * 256 * 2);      // 51.25 MB
    ushort_t* Bst  = (ushort_t*)alloc((size_t)NPAD * 256 * 2);      // 51.25 MB
    ushort_t* WC   = (ushort_t*)alloc(7340032UL * 2);               // 14.7 MB
    ushort_t* lsiC = (ushort_t*)alloc(1536 * 2);
    ushort_t* lbiC = (ushort_t*)alloc(1536 * 2);
    ushort_t* dbiC = (ushort_t*)alloc(1536 * 2);
    ushort_t* lsoC = (ushort_t*)alloc(1024 * 2);
    ushort_t* lboC = (ushort_t*)alloc(1024 * 2);
    ushort_t* dboC = (ushort_t*)alloc(512 * 2);
    ushort_t* dWiC = (ushort_t*)alloc(393216UL * 2);
    ushort_t* dWoC = (ushort_t*)alloc(262144UL * 2);
    ushort_t* dWiS = (ushort_t*)alloc(393216UL * 2);                // ls-scaled inner dense W
    ushort_t* dWoS = (ushort_t*)alloc(262144UL * 2);                // ls-scaled out dense W
    float* uwi     = (float*)alloc(1536 * 4);
    float* w0i     = (float*)alloc(1536 * 4);
    float* uwo     = (float*)alloc(512 * 4);
    float* w0o     = (float*)alloc(512 * 4);
    float* Sg      = (float*)alloc((size_t)NPAD * 4);
    float* Sq      = (float*)alloc((size_t)NPAD * 4);
    float2* MR     = (float2*)alloc((size_t)NPAD * 8);
    int* flag      = (int*)alloc(256);
    int* counts    = (int*)alloc((size_t)N_NODES * 4);
    int* incl      = (int*)alloc((size_t)N_NODES * 4);
    int* chsums    = (int*)alloc(1024);
    int* chunkoff  = (int*)alloc(1024);
    int* offsets   = (int*)alloc((size_t)(N_NODES + 8) * 4);
    int* cursor    = (int*)alloc((size_t)N_NODES * 4);
    int* sorted    = (int*)alloc((size_t)NE * 4);
    ushort_t* G    = (ushort_t*)alloc((size_t)NPAD * 512 * 2);      // 102.5 MB gelu(msg) (inner: 256 cols)
    // Third state buffer: prefer d_out (f32 harness -> 102.4 MB), else ws.
    ushort_t* R;
    if ((size_t)out_size >= (size_t)NPAD * 256 * 2) R = (ushort_t*)d_out;
    else R = (ushort_t*)alloc((size_t)NPAD * 256 * 2);
    size_t fixed = (size_t)(w - (char*)d_ws);

    // Big shared scratch: Zq [NPAD,512] fp16
    const size_t ZQ_BYTES = (size_t)NPAD * 512 * 2;                 // 102,498,304
    size_t bigsz = (ws_size > fixed) ? (ws_size - fixed) : 0;
    if (bigsz < ZQ_BYTES) {
        fprintf(stderr, "kernel_launch: ws too small (%zu bytes, fixed %zu, big %zu) -- no-op\n",
                ws_size, fixed, bigsz);
        return;
    }
    ushort_t* Zq = (ushort_t*)w;     // [NPAD,512] fp16 chunk

    // ---- setup: dtype detect, canonicalize, CSR, embed, weight pack ----
    detect_k<<<1, 256, 0, stream>>>((const unsigned*)tab, flag);
    CvtArgs ca;
    ca.src[0] = lsi;  ca.dst[0] = lsiC; ca.n[0] = 1536;
    ca.src[1] = lbi;  ca.dst[1] = lbiC; ca.n[1] = 1536;
    ca.src[2] = dbi;  ca.dst[2] = dbiC; ca.n[2] = 1536;
    ca.src[3] = lso;  ca.dst[3] = lsoC; ca.n[3] = 1024;
    ca.src[4] = lbo;  ca.dst[4] = lboC; ca.n[4] = 1024;
    ca.src[5] = dbo;  ca.dst[5] = dboC; ca.n[5] = 512;
    ca.src[6] = dWi;  ca.dst[6] = dWiC; ca.n[6] = 393216;
    ca.src[7] = dWo;  ca.dst[7] = dWoC; ca.n[7] = 262144;
    cvt_k<<<dim3(1536, 8), 256, 0, stream>>>(ca, flag);
    scale_w_k<<<512, 256, 0, stream>>>(dWiC, lsiC, lbiC, dbiC, dWoC, lsoC, lboC, dboC,
                                       dWiS, uwi, w0i, dWoS, uwo, w0o);
    hipMemsetAsync(counts, 0, (size_t)N_NODES * 4, stream);
    hipMemsetAsync(Sg, 0, (size_t)NPAD * 4, stream);
    hipMemsetAsync(Sq, 0, (size_t)NPAD * 4, stream);
    // zero pad rows (100000..100095) of the three state buffers once
    hipMemsetAsync(A   + (size_t)N_NODES * 256, 0, (size_t)(NPAD - N_NODES) * 256 * 2, stream);
    hipMemsetAsync(Bst + (size_t)N_NODES * 256, 0, (size_t)(NPAD - N_NODES) * 256 * 2, stream);
    hipMemsetAsync(R   + (size_t)N_NODES * 256, 0, (size_t)(NPAD - N_NODES) * 256 * 2, stream);
    pack_w<<<28672, 256, 0, stream>>>(eWi, eWo, WC, flag);
    embed_k<<<N_NODES / 4, 256, 0, stream>>>(ids, tab, A, flag);
    count_k<<<(NE + 255) / 256, 256, 0, stream>>>(etgt, counts);
    scan1_k<<<NCH, 256, 0, stream>>>(counts, incl, chsums);
    scan2_k<<<1, 256, 0, stream>>>(chsums, chunkoff);
    scan3_k<<<NCH, 256, 0, stream>>>(counts, incl, chunkoff, offsets, cursor);
    fill_k<<<(NE + 255) / 256, 256, 0, stream>>>(et, esrc, etgt, cursor, sorted);

    // ---- inner layer: 4x(Z-gemm + agg/gelu/stats) -> stats -> LN-folded dense ----
    auto inner_layer = [&](const ushort_t* Xin, ushort_t* Xout, int lay) {
        for (int q = 0; q < 4; q++) {
            gemm_bt<3><<<dim3(4, NTILES), 256, 0, stream>>>(
                Xin, WC + (long)lay * 524288 + (long)q * 131072, 256, 512, Zq,
                nullptr, nullptr, nullptr, 0);
            agg_q<<<NPAD / 4, 256, 0, stream>>>(Zq, offsets, sorted, G, 256, q, Sg, Sq);
        }
        stats_k<<<(N_NODES + 255) / 256, 256, 0, stream>>>(Sg, Sq, MR, 1.f / 256.f);
        gemm_bt<2><<<dim3(2, NTILES), 256, 0, stream>>>(G, dWiS + (long)lay * 65536, 256, 256,
                                                        Xout, MR, uwi + lay * 256, w0i + lay * 256, N_NODES);
    };

    // ---- out layer: 8x(split-A Z-gemm + agg/gelu/stats) -> stats -> dense ----
    auto out_layer = [&](const ushort_t* X0, const ushort_t* X1, int b, ushort_t* dest) {
        for (int c = 0; c < 8; c++) {
            gemm_bt2<<<dim3(4, NTILES), 256, 0, stream>>>(
                X0, X1, WC + WCO_OFF + (long)b * 2097152 + (long)c * 262144, 512, Zq);
            agg_q<<<NPAD / 4, 256, 0, stream>>>(Zq, offsets, sorted, G, 512, c, Sg, Sq);
        }
        stats_k<<<(N_NODES + 255) / 256, 256, 0, stream>>>(Sg, Sq, MR, 1.f / 512.f);
        gemm_bt<2><<<dim3(2, NTILES), 256, 0, stream>>>(G, dWoS + (long)b * 131072, 512, 256,
                                                        dest, MR, uwo + b * 256, w0o + b * 256, N_NODES);
    };

    // block 0: state A (embed). inner: A->Bst, Bst->R, R->Bst. out [A|Bst] -> R
    inner_layer(A, Bst, 0);
    inner_layer(Bst, R, 1);
    inner_layer(R, Bst, 2);
    out_layer(A, Bst, 0, R);
    // block 1: state R. inner: R->A, A->Bst, Bst->A. out [R|A] -> Bst
    inner_layer(R, A, 3);
    inner_layer(A, Bst, 4);
    inner_layer(Bst, A, 5);
    out_layer(R, A, 1, Bst);

    emit_k<<<(OUT_ELEMS + 255) / 256, 256, 0, stream>>>(Bst, d_out, flag);
}

// Round 8
// 5976.199 us; speedup vs baseline: 1.0701x; 1.0701x over previous
//
#include <hip/hip_runtime.h>
#include <cstdio>

#define N_NODES 100000
#define NPAD    100096      // 782*128 padded row count (gemm reads full tiles)
#define NTILES  782         // ceil(100000/128)
#define NE      320000
#define NCH     196         // ceil(100000/512)
#define WCO_OFF 3145728L    // 6*256*2048 inner W elems (quarter-Z layout)
#define OUT_ELEMS (N_NODES * 256)

typedef unsigned short ushort_t;
typedef unsigned short u16x4 __attribute__((ext_vector_type(4)));
typedef unsigned short u16x8 __attribute__((ext_vector_type(8)));
typedef _Float16       f16;
typedef _Float16       f16x8 __attribute__((ext_vector_type(8)));
typedef float          f32x4 __attribute__((ext_vector_type(4)));
typedef float          f32x4v __attribute__((ext_vector_type(4)));

__device__ __forceinline__ float bf2f(ushort_t u) {
    return __uint_as_float(((unsigned)u) << 16);
}
__device__ __forceinline__ ushort_t f2bf(float f) {
    unsigned u = __float_as_uint(f);
    u += 0x7FFFu + ((u >> 16) & 1u);   // round-to-nearest-even
    return (ushort_t)(u >> 16);
}
__device__ __forceinline__ ushort_t f2h(float f) {
    f16 h = (f16)f;
    return __builtin_bit_cast(ushort_t, h);
}
__device__ __forceinline__ float h2f(ushort_t u) {
    return (float)__builtin_bit_cast(f16, u);
}

// ---------------------------------------------------------------------------
// XCD-aware bijective block remap (m204 variant; handles nwg % 8 != 0).
// ---------------------------------------------------------------------------
__device__ __forceinline__ int xcd_remap(int pbid, int nwg) {
    int q = nwg >> 3, r = nwg & 7;
    int xcd = pbid & 7, idx = pbid >> 3;
    int base = (xcd < r) ? xcd * (q + 1) : r * (q + 1) + (xcd - r) * q;
    return base + idx;
}

// fast tanh: clamp + exp identity (abs err ~1e-6, invisible in fp16)
__device__ __forceinline__ float fast_tanh(float x) {
    x = fminf(fmaxf(x, -10.f), 10.f);
    float e = __expf(2.f * x);
    return (e - 1.f) / (e + 1.f);
}

__device__ __forceinline__ float gelu_f(float x) {
    return 0.5f * x * (1.f + erff(x * 0.70710678118654752f));
}

// ---------------------------------------------------------------------------
// dtype sniff on embed_table words. flag = 1 means float32 inputs.
// ---------------------------------------------------------------------------
__global__ __launch_bounds__(256) void detect_k(const unsigned* __restrict__ w0, int* __restrict__ flag) {
    __shared__ int lds[256];
    int t = threadIdx.x;
    int cnt = 0;
    for (int i = t; i < 2048; i += 256) {
        unsigned e = (w0[i] >> 7) & 0xFFu;
        cnt += (e >= 96u && e <= 140u) ? 1 : 0;
    }
    lds[t] = cnt; __syncthreads();
    for (int s = 128; s > 0; s >>= 1) {
        if (t < s) lds[t] += lds[t + s];
        __syncthreads();
    }
    if (t == 0) *flag = (lds[0] < 1024) ? 1 : 0;
}

// input element -> canonical fp16 bits
__device__ __forceinline__ ushort_t load_in(const void* p, long i, bool isf32) {
    return isf32 ? f2h(((const float*)p)[i]) : f2h(bf2f(((const ushort_t*)p)[i]));
}

// ---------------------------------------------------------------------------
// small-tensor fp16 canonicalization (ln scales/biases, dense W/b)
// ---------------------------------------------------------------------------
struct CvtArgs {
    const void* src[8];
    ushort_t*   dst[8];
    int         n[8];
};

__global__ __launch_bounds__(256) void cvt_k(CvtArgs a, const int* __restrict__ flag) {
    int ti = blockIdx.y;
    int n = a.n[ti];
    const void* s = a.src[ti];
    ushort_t* d = a.dst[ti];
    bool isf32 = (*flag != 0);
    for (int i = blockIdx.x * 256 + threadIdx.x; i < n; i += gridDim.x * 256)
        d[i] = load_in(s, i, isf32);
}

// ---------------------------------------------------------------------------
// LN-folded dense weight prep (runs after cvt_k). Wave per output row.
// ---------------------------------------------------------------------------
__global__ __launch_bounds__(256) void scale_w_k(const ushort_t* __restrict__ dWiC,
                                                 const ushort_t* __restrict__ lsiC,
                                                 const ushort_t* __restrict__ lbiC,
                                                 const ushort_t* __restrict__ dbiC,
                                                 const ushort_t* __restrict__ dWoC,
                                                 const ushort_t* __restrict__ lsoC,
                                                 const ushort_t* __restrict__ lboC,
                                                 const ushort_t* __restrict__ dboC,
                                                 ushort_t* __restrict__ dWiS,
                                                 float* __restrict__ uwi, float* __restrict__ w0i,
                                                 ushort_t* __restrict__ dWoS,
                                                 float* __restrict__ uwo, float* __restrict__ w0o) {
    int wid = blockIdx.x * 4 + (threadIdx.x >> 6);
    int l = threadIdx.x & 63;
    float u = 0.f, w0 = 0.f;
    if (wid < 1536) {
        int lay = wid >> 8, c = wid & 255;
        u16x4 wv = *(const u16x4*)(dWiC + (size_t)wid * 256 + l * 4);
        u16x4 sv = *(const u16x4*)(lsiC + lay * 256 + l * 4);
        u16x4 bv = *(const u16x4*)(lbiC + lay * 256 + l * 4);
        u16x4 ov;
        #pragma unroll
        for (int i = 0; i < 4; i++) {
            float W = h2f(wv[i]);
            float ws = W * h2f(sv[i]);
            ov[i] = f2h(ws);
            u += ws; w0 += W * h2f(bv[i]);
        }
        *(u16x4*)(dWiS + (size_t)wid * 256 + l * 4) = ov;
        #pragma unroll
        for (int m = 1; m < 64; m <<= 1) {
            u += __shfl_xor(u, m, 64); w0 += __shfl_xor(w0, m, 64);
        }
        if (l == 0) { uwi[wid] = u; w0i[wid] = w0 + h2f(dbiC[lay * 256 + c]); }
    } else if (wid < 2048) {
        int w2 = wid - 1536;
        int b = w2 >> 8, c = w2 & 255;
        u16x8 wv = *(const u16x8*)(dWoC + (size_t)w2 * 512 + l * 8);
        u16x8 sv = *(const u16x8*)(lsoC + b * 512 + l * 8);
        u16x8 bv = *(const u16x8*)(lboC + b * 512 + l * 8);
        u16x8 ov;
        #pragma unroll
        for (int i = 0; i < 8; i++) {
            float W = h2f(wv[i]);
            float ws = W * h2f(sv[i]);
            ov[i] = f2h(ws);
            u += ws; w0 += W * h2f(bv[i]);
        }
        *(u16x8*)(dWoS + (size_t)w2 * 512 + l * 8) = ov;
        #pragma unroll
        for (int m = 1; m < 64; m <<= 1) {
            u += __shfl_xor(u, m, 64); w0 += __shfl_xor(w0, m, 64);
        }
        if (l == 0) { uwo[w2] = u; w0o[w2] = w0 + h2f(dboC[b * 256 + c]); }
    }
}

// ---------------------------------------------------------------------------
// Weight pre-pack (dual dtype -> fp16), both stacks in quarter-Z layout.
// ---------------------------------------------------------------------------
__global__ __launch_bounds__(256) void pack_w(const void* __restrict__ eWi,
                                              const void* __restrict__ eWo,
                                              ushort_t* __restrict__ WC,
                                              const int* __restrict__ flag) {
    long idx = (long)blockIdx.x * 256 + threadIdx.x;
    bool isf32 = (*flag != 0);
    const long ELI = 6L * 4 * 256 * 512;     // 3,145,728
    const long ELO = 2L * 4 * 512 * 1024;    // 4,194,304
    if (idx < ELI) {
        int j = idx & 511;
        int o = (idx >> 9) & 255;
        int t = (idx >> 17) & 3;
        long l = idx >> 19;
        int q = o >> 6, oo = o & 63;
        int k = j & 255;
        int n = ((j < 256) ? 0 : 256) + t * 64 + oo;
        WC[l * 524288 + (long)q * 131072 + (long)n * 256 + k] = load_in(eWi, idx, isf32);
    } else if (idx < ELI + ELO) {
        long i2 = idx - ELI;
        int j = i2 & 1023;
        int o = (i2 >> 10) & 511;
        int t = (i2 >> 19) & 3;
        long b = i2 >> 21;
        int c = o >> 6, oo = o & 63;
        int k = j & 511;
        int n = ((j < 512) ? 0 : 256) + t * 64 + oo;
        WC[WCO_OFF + b * 2097152L + (long)c * 262144 + (long)n * 512 + k] = load_in(eWo, i2, isf32);
    }
}

// ---------------------------------------------------------------------------
// Embedding gather (dual dtype): S[v] = fp16(table[ids[v]])
// ---------------------------------------------------------------------------
__global__ __launch_bounds__(256) void embed_k(const int* __restrict__ ids,
                                               const void* __restrict__ tab,
                                               ushort_t* __restrict__ S,
                                               const int* __restrict__ flag) {
    int row = blockIdx.x * 4 + (threadIdx.x >> 6);
    int l = threadIdx.x & 63;
    if (row >= N_NODES) return;
    int id = ids[row];
    u16x4 v;
    if (*flag) {
        f32x4v fv = *(const f32x4v*)((const float*)tab + (size_t)id * 256 + l * 4);
        #pragma unroll
        for (int i = 0; i < 4; i++) v[i] = f2h(fv[i]);
    } else {
        u16x4 bv = *(const u16x4*)((const ushort_t*)tab + (size_t)id * 256 + l * 4);
        #pragma unroll
        for (int i = 0; i < 4; i++) v[i] = f2h(bf2f(bv[i]));
    }
    *(u16x4*)(S + (size_t)row * 256 + l * 4) = v;
}

// ---------------------------------------------------------------------------
// Output emit: internal fp16 -> harness dtype (f32 or bf16)
// ---------------------------------------------------------------------------
__global__ __launch_bounds__(256) void emit_k(const ushort_t* __restrict__ Bst, void* __restrict__ out,
                                              const int* __restrict__ flag) {
    long i = (long)blockIdx.x * 256 + threadIdx.x;
    if (i >= OUT_ELEMS) return;
    float v = h2f(Bst[i]);
    if (*flag) ((float*)out)[i] = v;
    else       ((ushort_t*)out)[i] = f2bf(v);
}

// ---------------------------------------------------------------------------
// CSR by target node
// ---------------------------------------------------------------------------
__global__ __launch_bounds__(256) void count_k(const int* __restrict__ tgt, int* __restrict__ counts) {
    int e = blockIdx.x * 256 + threadIdx.x;
    if (e < NE) atomicAdd(&counts[tgt[e]], 1);
}

__global__ __launch_bounds__(256) void scan1_k(const int* __restrict__ counts,
                                               int* __restrict__ incl, int* __restrict__ chsums) {
    __shared__ int lds[256];
    int c = blockIdx.x, t = threadIdx.x;
    int i0 = c * 512 + 2 * t;
    int a = (i0 < N_NODES) ? counts[i0] : 0;
    int b = (i0 + 1 < N_NODES) ? counts[i0 + 1] : 0;
    int ps = a + b;
    lds[t] = ps; __syncthreads();
    int x = ps;
    for (int off = 1; off < 256; off <<= 1) {
        int y = (t >= off) ? lds[t - off] : 0;
        __syncthreads();
        x += y; lds[t] = x;
        __syncthreads();
    }
    int excl = x - ps;
    if (i0 < N_NODES) incl[i0] = excl + a;
    if (i0 + 1 < N_NODES) incl[i0 + 1] = excl + a + b;
    if (t == 255) chsums[c] = x;
}

__global__ __launch_bounds__(256) void scan2_k(const int* __restrict__ chsums, int* __restrict__ chunkoff) {
    __shared__ int lds[256];
    int t = threadIdx.x;
    int v = (t < NCH) ? chsums[t] : 0;
    lds[t] = v; __syncthreads();
    int x = v;
    for (int off = 1; off < 256; off <<= 1) {
        int y = (t >= off) ? lds[t - off] : 0;
        __syncthreads();
        x += y; lds[t] = x;
        __syncthreads();
    }
    if (t <= NCH) chunkoff[t] = x - v;   // exclusive
}

__global__ __launch_bounds__(256) void scan3_k(const int* __restrict__ counts, const int* __restrict__ incl,
                                               const int* __restrict__ chunkoff,
                                               int* __restrict__ offsets, int* __restrict__ cursor) {
    int c = blockIdx.x, t = threadIdx.x;
    int base = chunkoff[c];
    #pragma unroll
    for (int k = 0; k < 2; k++) {
        int i = c * 512 + 2 * t + k;
        if (i < N_NODES) {
            int off = base + incl[i] - counts[i];
            offsets[i] = off;
            cursor[i] = off;
        }
    }
    if (c == 0 && t == 0) offsets[N_NODES] = chunkoff[NCH];
}

__global__ __launch_bounds__(256) void fill_k(const int* __restrict__ et, const int* __restrict__ src,
                                              const int* __restrict__ tgt,
                                              int* __restrict__ cursor, int* __restrict__ sorted) {
    int e = blockIdx.x * 256 + threadIdx.x;
    if (e < NE) {
        int pos = atomicAdd(&cursor[tgt[e]], 1);
        sorted[pos] = ((et[e] - 1) << 28) | src[e];
    }
}

// ---------------------------------------------------------------------------
// GEMM: C[localM, ldc] = A[localM, K] @ B[., K]^T  (fp16 row-major)
// 128x128 tile, BK=64, 4 waves, mfma_f32_16x16x32_f16, global_load_lds(16B).
// XCD-remapped blocks; XOR-swizzled LDS (pre-swizzled global source, rule #21);
// swapped-operand MFMA so each lane owns 4 consecutive C cols (u16x4 stores).
// EPI 2: LN-folded dense: val = rs_r*(acc - mean_r*u[c]) + w0[c]; tanh; fp16.
// EPI 3: Cb = fp16(acc)   (Z emit, unguarded/padded)
// ---------------------------------------------------------------------------
template<int EPI>
__global__ __launch_bounds__(256) void gemm_bt(const ushort_t* __restrict__ A,
                                               const ushort_t* __restrict__ B,
                                               int K, int ldc,
                                               ushort_t* __restrict__ Cb,
                                               const float2* __restrict__ MR,
                                               const float* __restrict__ uu,
                                               const float* __restrict__ w0t,
                                               int storeM) {
    __shared__ __align__(16) ushort_t As[128 * 64];
    __shared__ __align__(16) ushort_t Bs[128 * 64];
    const int tid = threadIdx.x;
    const int w = tid >> 6, l = tid & 63;
    const int wr = w >> 1, wc = w & 1;
    const int gx = gridDim.x;
    const int lbid = xcd_remap(blockIdx.y * gx + blockIdx.x, gx * gridDim.y);
    const long m0 = (long)(lbid / gx) * 128, n0 = (long)(lbid % gx) * 128;
    const int lr = l >> 3;
    const int lc = (l & 7) * 8;
    const int cbk = ((l & 7) ^ lr) * 8;      // swizzled global col-block (LDS stays linear)
    f32x4 acc[4][4];
    #pragma unroll
    for (int s = 0; s < 4; s++)
        #pragma unroll
        for (int n = 0; n < 4; n++) acc[s][n] = (f32x4){0.f, 0.f, 0.f, 0.f};

    for (int k0 = 0; k0 < K; k0 += 64) {
        #pragma unroll
        for (int q = 0; q < 4; q++) {
            int row = w * 32 + q * 8 + lr;
            const ushort_t* g = A + (m0 + row) * (long)K + k0 + cbk;
            __builtin_amdgcn_global_load_lds(
                (__attribute__((address_space(1))) unsigned int*)(g),
                (__attribute__((address_space(3))) unsigned int*)(&As[row * 64 + lc]), 16, 0, 0);
        }
        #pragma unroll
        for (int q = 0; q < 4; q++) {
            int row = w * 32 + q * 8 + lr;
            const ushort_t* g = B + (n0 + row) * (long)K + k0 + cbk;
            __builtin_amdgcn_global_load_lds(
                (__attribute__((address_space(1))) unsigned int*)(g),
                (__attribute__((address_space(3))) unsigned int*)(&Bs[row * 64 + lc]), 16, 0, 0);
        }
        __syncthreads();
        #pragma unroll
        for (int kk = 0; kk < 2; kk++) {
            f16x8 af[4], bfr[4];
            const int gb = kk * 4 + (l >> 4);
            const int sb = (gb ^ (l & 7)) * 8;   // swizzled LDS col offset
            #pragma unroll
            for (int s = 0; s < 4; s++)
                af[s] = *(const f16x8*)&As[(wr * 64 + s * 16 + (l & 15)) * 64 + sb];
            #pragma unroll
            for (int n = 0; n < 4; n++)
                bfr[n] = *(const f16x8*)&Bs[(wc * 64 + n * 16 + (l & 15)) * 64 + sb];
            #pragma unroll
            for (int s = 0; s < 4; s++)
                #pragma unroll
                for (int n = 0; n < 4; n++)
                    acc[s][n] = __builtin_amdgcn_mfma_f32_16x16x32_f16(bfr[n], af[s], acc[s][n], 0, 0, 0);
        }
        __syncthreads();
    }
    // Transposed fragment: lane owns row r0+s*16, cols c0+n*16 .. +3 (consecutive)
    const long r0 = m0 + wr * 64 + (l & 15);
    const long c0 = n0 + wc * 64 + ((l >> 4) << 2);
    #pragma unroll
    for (int s = 0; s < 4; s++) {
        long r = r0 + s * 16;
        if constexpr (EPI == 2) {
            if (r < storeM) {
                float2 mr = MR[r];
                #pragma unroll
                for (int n = 0; n < 4; n++) {
                    long c = c0 + n * 16;
                    f32x4v u4 = *(const f32x4v*)&uu[c];
                    f32x4v w4 = *(const f32x4v*)&w0t[c];
                    u16x4 o;
                    #pragma unroll
                    for (int j = 0; j < 4; j++)
                        o[j] = f2h(fast_tanh(mr.y * (acc[s][n][j] - mr.x * u4[j]) + w4[j]));
                    *(u16x4*)&Cb[r * ldc + c] = o;
                }
            }
        } else {
            #pragma unroll
            for (int n = 0; n < 4; n++) {
                long c = c0 + n * 16;
                u16x4 o;
                #pragma unroll
                for (int j = 0; j < 4; j++) o[j] = f2h(acc[s][n][j]);
                *(u16x4*)&Cb[r * ldc + c] = o;
            }
        }
    }
}

// ---------------------------------------------------------------------------
// Split-A GEMM for out-layer Z: A = [A0 | A1] (two [.,256] fp16 buffers),
// K = 512 fixed, fp16 store. Same swizzle + transposed-store structure.
// ---------------------------------------------------------------------------
__global__ __launch_bounds__(256) void gemm_bt2(const ushort_t* __restrict__ A0,
                                                const ushort_t* __restrict__ A1,
                                                const ushort_t* __restrict__ B,
                                                int ldc,
                                                ushort_t* __restrict__ Cb) {
    __shared__ __align__(16) ushort_t As[128 * 64];
    __shared__ __align__(16) ushort_t Bs[128 * 64];
    const int tid = threadIdx.x;
    const int w = tid >> 6, l = tid & 63;
    const int wr = w >> 1, wc = w & 1;
    const int gx = gridDim.x;
    const int lbid = xcd_remap(blockIdx.y * gx + blockIdx.x, gx * gridDim.y);
    const long m0 = (long)(lbid / gx) * 128, n0 = (long)(lbid % gx) * 128;
    const int lr = l >> 3;
    const int lc = (l & 7) * 8;
    const int cbk = ((l & 7) ^ lr) * 8;
    f32x4 acc[4][4];
    #pragma unroll
    for (int s = 0; s < 4; s++)
        #pragma unroll
        for (int n = 0; n < 4; n++) acc[s][n] = (f32x4){0.f, 0.f, 0.f, 0.f};

    for (int k0 = 0; k0 < 512; k0 += 64) {
        const ushort_t* Ab = (k0 < 256) ? A0 : A1;
        const int kq = k0 & 255;
        #pragma unroll
        for (int q = 0; q < 4; q++) {
            int row = w * 32 + q * 8 + lr;
            const ushort_t* g = Ab + (m0 + row) * 256L + kq + cbk;
            __builtin_amdgcn_global_load_lds(
                (__attribute__((address_space(1))) unsigned int*)(g),
                (__attribute__((address_space(3))) unsigned int*)(&As[row * 64 + lc]), 16, 0, 0);
        }
        #pragma unroll
        for (int q = 0; q < 4; q++) {
            int row = w * 32 + q * 8 + lr;
            const ushort_t* g = B + (n0 + row) * 512L + k0 + cbk;
            __builtin_amdgcn_global_load_lds(
                (__attribute__((address_space(1))) unsigned int*)(g),
                (__attribute__((address_space(3))) unsigned int*)(&Bs[row * 64 + lc]), 16, 0, 0);
        }
        __syncthreads();
        #pragma unroll
        for (int kk = 0; kk < 2; kk++) {
            f16x8 af[4], bfr[4];
            const int gb = kk * 4 + (l >> 4);
            const int sb = (gb ^ (l & 7)) * 8;
            #pragma unroll
            for (int s = 0; s < 4; s++)
                af[s] = *(const f16x8*)&As[(wr * 64 + s * 16 + (l & 15)) * 64 + sb];
            #pragma unroll
            for (int n = 0; n < 4; n++)
                bfr[n] = *(const f16x8*)&Bs[(wc * 64 + n * 16 + (l & 15)) * 64 + sb];
            #pragma unroll
            for (int s = 0; s < 4; s++)
                #pragma unroll
                for (int n = 0; n < 4; n++)
                    acc[s][n] = __builtin_amdgcn_mfma_f32_16x16x32_f16(bfr[n], af[s], acc[s][n], 0, 0, 0);
        }
        __syncthreads();
    }
    const long r0 = m0 + wr * 64 + (l & 15);
    const long c0 = n0 + wc * 64 + ((l >> 4) << 2);
    #pragma unroll
    for (int s = 0; s < 4; s++) {
        long r = r0 + s * 16;
        #pragma unroll
        for (int n = 0; n < 4; n++) {
            long c = c0 + n * 16;
            u16x4 o;
            #pragma unroll
            for (int j = 0; j < 4; j++) o[j] = f2h(acc[s][n][j]);
            *(u16x4*)&Cb[r * ldc + c] = o;
        }
    }
}

// ---------------------------------------------------------------------------
// Chunk-aggregate over Z + fused gelu + LN-stats accumulation.
// ---------------------------------------------------------------------------
__global__ __launch_bounds__(256) void agg_q(const ushort_t* __restrict__ Z,
                                             const int* __restrict__ offsets,
                                             const int* __restrict__ sorted,
                                             ushort_t* __restrict__ G, int mld, int q,
                                             float* __restrict__ Sg, float* __restrict__ Sq) {
    int v = blockIdx.x * 4 + (threadIdx.x >> 6);
    int l = threadIdx.x & 63;
    if (v >= NPAD) return;
    ushort_t* mp = G + (size_t)v * mld + (q << 6) + l;
    if (v >= N_NODES) { *mp = 0; return; }
    float acc = 0.f;
    int d0 = 0, d1 = 0, d2 = 0, d3 = 0;
    int beg = offsets[v], end = offsets[v + 1];
    for (int e = beg; e < end; ++e) {
        int pk = sorted[e];
        int t = pk >> 28;                 // 0..3
        int s = pk & 0x0FFFFFFF;
        acc += h2f(Z[(size_t)s * 512 + (t << 6) + l]);
        d0 += (t == 0); d1 += (t == 1); d2 += (t == 2); d3 += (t == 3);
    }
    const ushort_t* zs = Z + (size_t)v * 512 + 256 + l;
    if (d0) acc += (float)d0 * h2f(zs[0]);
    if (d1) acc += (float)d1 * h2f(zs[64]);
    if (d2) acc += (float)d2 * h2f(zs[128]);
    if (d3) acc += (float)d3 * h2f(zs[192]);
    float g = gelu_f(acc);
    *mp = f2h(g);
    float sg = g, sq = g * g;
    #pragma unroll
    for (int m = 1; m < 64; m <<= 1) {
        sg += __shfl_xor(sg, m, 64);
        sq += __shfl_xor(sq, m, 64);
    }
    if (l == 0) {
        atomicAdd(&Sg[v], sg);
        atomicAdd(&Sq[v], sq);
    }
}

// ---------------------------------------------------------------------------
// Per-node LN stats: MR[v] = (mean, rsqrt(var+eps)); re-zero Sg/Sq for reuse.
// ---------------------------------------------------------------------------
__global__ __launch_bounds__(256) void stats_k(float* __restrict__ Sg, float* __restrict__ Sq,
                                               float2* __restrict__ MR, float inv) {
    int v = blockIdx.x * 256 + threadIdx.x;
    if (v >= N_NODES) return;
    float mean = Sg[v] * inv;
    float var = fmaxf(Sq[v] * inv - mean * mean, 0.f);
    MR[v] = make_float2(mean, rsqrtf(var + 1e-5f));
    Sg[v] = 0.f; Sq[v] = 0.f;
}

// ---------------------------------------------------------------------------
extern "C" void kernel_launch(void* const* d_in, const int* in_sizes, int n_in,
                              void* d_out, int out_size, void* d_ws, size_t ws_size,
                              hipStream_t stream) {
    const int* ids = (const int*)d_in[0];
    const int* te = (const int*)d_in[1];
    const int* et = te;
    const int* esrc = te + NE;
    const int* etgt = te + 2 * NE;
    const void* tab = d_in[2];
    const void* eWi = d_in[3];
    const void* lsi = d_in[4];
    const void* lbi = d_in[5];
    const void* dWi = d_in[6];
    const void* dbi = d_in[7];
    const void* eWo = d_in[8];
    const void* lso = d_in[9];
    const void* lbo = d_in[10];
    const void* dWo = d_in[11];
    const void* dbo = d_in[12];

    char* w = (char*)d_ws;
    auto alloc = [&](size_t bytes) -> char* {
        char* p = w; w += (bytes + 255) & ~(size_t)255; return p;
    };
    ushort_t* A    = (ushort_t*)alloc((size_t)NPAD * 256 * 2);      // 51.25 MB
    ushort_t* Bst  = (ushort_t*)alloc((size_t)NPAD * 256 * 2);      // 51.25 MB
    ushort_t* WC   = (ushort_t*)alloc(7340032UL * 2);               // 14.7 MB
    ushort_t* lsiC = (ushort_t*)alloc(1536 * 2);
    ushort_t* lbiC = (ushort_t*)alloc(1536 * 2);
    ushort_t* dbiC = (ushort_t*)alloc(1536 * 2);
    ushort_t* lsoC = (ushort_t*)alloc(1024 * 2);
    ushort_t* lboC = (ushort_t*)alloc(1024 * 2);
    ushort_t* dboC = (ushort_t*)alloc(512 * 2);
    ushort_t* dWiC = (ushort_t*)alloc(393216UL * 2);
    ushort_t* dWoC = (ushort_t*)alloc(262144UL * 2);
    ushort_t* dWiS = (ushort_t*)alloc(393216UL * 2);                // ls-scaled inner dense W
    ushort_t* dWoS = (ushort_t*)alloc(262144UL * 2);                // ls-scaled out dense W
    float* uwi     = (float*)alloc(1536 * 4);
    float* w0i     = (float*)alloc(1536 * 4);
    float* uwo     = (float*)alloc(512 * 4);
    float* w0o     = (float*)alloc(512 * 4);
    float* Sg      = (float*)alloc((size_t)NPAD * 4);
    float* Sq      = (float*)alloc((size_t)NPAD * 4);
    float2* MR     = (float2*)alloc((size_t)NPAD * 8);
    int* flag      = (int*)alloc(256);
    int* counts    = (int*)alloc((size_t)N_NODES * 4);
    int* incl      = (int*)alloc((size_t)N_NODES * 4);
    int* chsums    = (int*)alloc(1024);
    int* chunkoff  = (int*)alloc(1024);
    int* offsets   = (int*)alloc((size_t)(N_NODES + 8) * 4);
    int* cursor    = (int*)alloc((size_t)N_NODES * 4);
    int* sorted    = (int*)alloc((size_t)NE * 4);
    ushort_t* G    = (ushort_t*)alloc((size_t)NPAD * 512 * 2);      // 102.5 MB gelu(msg) (inner: 256 cols)
    // Third state buffer: prefer d_out (f32 harness -> 102.4 MB), else ws.
    ushort_t* R;
    if ((size_t)out_size >= (size_t)NPAD * 256 * 2) R = (ushort_t*)d_out;
    else R = (ushort_t*)alloc((size_t)NPAD * 256 * 2);
    size_t fixed = (size_t)(w - (char*)d_ws);

    // Big shared scratch: Zq [NPAD,512] fp16
    const size_t ZQ_BYTES = (size_t)NPAD * 512 * 2;                 // 102,498,304
    size_t bigsz = (ws_size > fixed) ? (ws_size - fixed) : 0;
    if (bigsz < ZQ_BYTES) {
        fprintf(stderr, "kernel_launch: ws too small (%zu bytes, fixed %zu, big %zu) -- no-op\n",
                ws_size, fixed, bigsz);
        return;
    }
    ushort_t* Zq = (ushort_t*)w;     // [NPAD,512] fp16 chunk

    // ---- setup: dtype detect, canonicalize, CSR, embed, weight pack ----
    detect_k<<<1, 256, 0, stream>>>((const unsigned*)tab, flag);
    CvtArgs ca;
    ca.src[0] = lsi;  ca.dst[0] = lsiC; ca.n[0] = 1536;
    ca.src[1] = lbi;  ca.dst[1] = lbiC; ca.n[1] = 1536;
    ca.src[2] = dbi;  ca.dst[2] = dbiC; ca.n[2] = 1536;
    ca.src[3] = lso;  ca.dst[3] = lsoC; ca.n[3] = 1024;
    ca.src[4] = lbo;  ca.dst[4] = lboC; ca.n[4] = 1024;
    ca.src[5] = dbo;  ca.dst[5] = dboC; ca.n[5] = 512;
    ca.src[6] = dWi;  ca.dst[6] = dWiC; ca.n[6] = 393216;
    ca.src[7] = dWo;  ca.dst[7] = dWoC; ca.n[7] = 262144;
    cvt_k<<<dim3(1536, 8), 256, 0, stream>>>(ca, flag);
    scale_w_k<<<512, 256, 0, stream>>>(dWiC, lsiC, lbiC, dbiC, dWoC, lsoC, lboC, dboC,
                                       dWiS, uwi, w0i, dWoS, uwo, w0o);
    hipMemsetAsync(counts, 0, (size_t)N_NODES * 4, stream);
    hipMemsetAsync(Sg, 0, (size_t)NPAD * 4, stream);
    hipMemsetAsync(Sq, 0, (size_t)NPAD * 4, stream);
    // zero pad rows (100000..100095) of the three state buffers once
    hipMemsetAsync(A   + (size_t)N_NODES * 256, 0, (size_t)(NPAD - N_NODES) * 256 * 2, stream);
    hipMemsetAsync(Bst + (size_t)N_NODES * 256, 0, (size_t)(NPAD - N_NODES) * 256 * 2, stream);
    hipMemsetAsync(R   + (size_t)N_NODES * 256, 0, (size_t)(NPAD - N_NODES) * 256 * 2, stream);
    pack_w<<<28672, 256, 0, stream>>>(eWi, eWo, WC, flag);
    embed_k<<<N_NODES / 4, 256, 0, stream>>>(ids, tab, A, flag);
    count_k<<<(NE + 255) / 256, 256, 0, stream>>>(etgt, counts);
    scan1_k<<<NCH, 256, 0, stream>>>(counts, incl, chsums);
    scan2_k<<<1, 256, 0, stream>>>(chsums, chunkoff);
    scan3_k<<<NCH, 256, 0, stream>>>(counts, incl, chunkoff, offsets, cursor);
    fill_k<<<(NE + 255) / 256, 256, 0, stream>>>(et, esrc, etgt, cursor, sorted);

    // ---- inner layer: 4x(Z-gemm + agg/gelu/stats) -> stats -> LN-folded dense ----
    auto inner_layer = [&](const ushort_t* Xin, ushort_t* Xout, int lay) {
        for (int q = 0; q < 4; q++) {
            gemm_bt<3><<<dim3(4, NTILES), 256, 0, stream>>>(
                Xin, WC + (long)lay * 524288 + (long)q * 131072, 256, 512, Zq,
                nullptr, nullptr, nullptr, 0);
            agg_q<<<NPAD / 4, 256, 0, stream>>>(Zq, offsets, sorted, G, 256, q, Sg, Sq);
        }
        stats_k<<<(N_NODES + 255) / 256, 256, 0, stream>>>(Sg, Sq, MR, 1.f / 256.f);
        gemm_bt<2><<<dim3(2, NTILES), 256, 0, stream>>>(G, dWiS + (long)lay * 65536, 256, 256,
                                                        Xout, MR, uwi + lay * 256, w0i + lay * 256, N_NODES);
    };

    // ---- out layer: 8x(split-A Z-gemm + agg/gelu/stats) -> stats -> dense ----
    auto out_layer = [&](const ushort_t* X0, const ushort_t* X1, int b, ushort_t* dest) {
        for (int c = 0; c < 8; c++) {
            gemm_bt2<<<dim3(4, NTILES), 256, 0, stream>>>(
                X0, X1, WC + WCO_OFF + (long)b * 2097152 + (long)c * 262144, 512, Zq);
            agg_q<<<NPAD / 4, 256, 0, stream>>>(Zq, offsets, sorted, G, 512, c, Sg, Sq);
        }
        stats_k<<<(N_NODES + 255) / 256, 256, 0, stream>>>(Sg, Sq, MR, 1.f / 512.f);
        gemm_bt<2><<<dim3(2, NTILES), 256, 0, stream>>>(G, dWoS + (long)b * 131072, 512, 256,
                                                        dest, MR, uwo + b * 256, w0o + b * 256, N_NODES);
    };

    // block 0: state A (embed). inner: A->Bst, Bst->R, R->Bst. out [A|Bst] -> R
    inner_layer(A, Bst, 0);
    inner_layer(Bst, R, 1);
    inner_layer(R, Bst, 2);
    out_layer(A, Bst, 0, R);
    // block 1: state R. inner: R->A, A->Bst, Bst->A. out [R|A] -> Bst
    inner_layer(R, A, 3);
    inner_layer(A, Bst, 4);
    inner_layer(Bst, A, 5);
    out_layer(R, A, 1, Bst);

    emit_k<<<(OUT_ELEMS + 255) / 256, 256, 0, stream>>>(Bst, d_out, flag);
}